// Round 3
// baseline (1326.398 us; speedup 1.0000x reference)
//
#include <hip/hip_runtime.h>
#include <cstddef>

// GCN encoder: 3x (GCNConv -> LeakyReLU -> BN) then mu/logstd GCNConv heads.
// Key identity: prop(x @ W) = prop(x) @ W  (propagation is linear, rowwise).
// prop(h)[d] = dinv[d] * ( sum_{e: dst=d} h[src_e]*dinv[src_e] + h[d]*dinv[d] )
// We compute hs = h*dinv, init agg = hs (self loop), scatter-add hs[src] into
// agg[dst], and fold the final *dinv[d] into the next GEMM's epilogue.

#define NEG_SLOPE 0.01f
#define BN_EPS 1e-5f

__global__ __launch_bounds__(256) void init_k(float* __restrict__ deg,
                                              float* __restrict__ bns, int N) {
  int i = blockIdx.x * 256 + threadIdx.x;
  if (i < N) deg[i] = 1.0f;      // self-loop
  if (i < 384) bns[i] = 0.0f;    // 3 layers x {sum[64], sumsq[64]}
}

__global__ __launch_bounds__(256) void degree_count(const int* __restrict__ dst,
                                                    float* __restrict__ deg, int E) {
  int e = blockIdx.x * 256 + threadIdx.x;
  if (e < E) atomicAdd(&deg[dst[e]], 1.0f);
}

__global__ __launch_bounds__(256) void finish_dinv(float* __restrict__ deg, int N) {
  int i = blockIdx.x * 256 + threadIdx.x;
  if (i < N) deg[i] = rsqrtf(deg[i]);   // deg >= 1 always (self loop)
}

// hs0 = x * dinv[row]; agg0 = hs0 (self-loop init). 3 channels.
__global__ __launch_bounds__(256) void scale0(const float* __restrict__ x,
                                              const float* __restrict__ dinv,
                                              float* __restrict__ hs0,
                                              float* __restrict__ agg0, int N) {
  int i = blockIdx.x * 256 + threadIdx.x;
  if (i >= N * 3) return;
  float v = x[i] * dinv[i / 3];
  hs0[i] = v;
  agg0[i] = v;
}

__global__ __launch_bounds__(256) void scatter3(const int* __restrict__ src,
                                                const int* __restrict__ dst,
                                                const float* __restrict__ hs,
                                                float* __restrict__ agg, int E) {
  int e = blockIdx.x * 256 + threadIdx.x;
  if (e >= E) return;
  int s = src[e], d = dst[e];
#pragma unroll
  for (int c = 0; c < 3; ++c) atomicAdd(&agg[d * 3 + c], hs[s * 3 + c]);
}

// one wave per edge, lane = channel (64 ch): coalesced 256B gather + atomics
__global__ __launch_bounds__(256) void scatter64(const int* __restrict__ src,
                                                 const int* __restrict__ dst,
                                                 const float* __restrict__ hs,
                                                 float* __restrict__ agg, int E) {
  int e = blockIdx.x * 4 + (threadIdx.x >> 6);
  if (e >= E) return;
  int lane = threadIdx.x & 63;
  int s = src[e], d = dst[e];
  atomicAdd(&agg[d * 64 + lane], hs[s * 64 + lane]);
}

// H = LeakyReLU(dinv[r]*(AGG @ W) + b), plus per-channel BN sum/sumsq partials.
// 64 rows x 64 cols per block, 256 threads, 4x4 micro-tile per thread.
template <int K>
__global__ __launch_bounds__(256) void gemm_bn(
    const float* __restrict__ AGG, const float* __restrict__ dinv,
    const float* __restrict__ W /*[K][64]*/, const float* __restrict__ b,
    float* __restrict__ H, float* __restrict__ bns, int N) {
  __shared__ __align__(16) float P[64][68];
  __shared__ __align__(16) float Ws[64][64];
  __shared__ float red1[16][64];
  __shared__ float red2[16][64];
  const int t = threadIdx.x;
  const int r0 = blockIdx.x * 64;

  if (K == 64) {
    for (int i = t; i < 1024; i += 256) {
      int r = i >> 4, k4 = (i & 15) << 2, gr = r0 + r;
      float4 v = make_float4(0.f, 0.f, 0.f, 0.f);
      if (gr < N) v = *(const float4*)(AGG + (size_t)gr * 64 + k4);
      *(float4*)&P[r][k4] = v;
    }
  } else {
    for (int i = t; i < 64 * 64; i += 256) {
      int r = i >> 6, k = i & 63, gr = r0 + r;
      P[r][k] = (k < K && gr < N) ? AGG[(size_t)gr * K + k] : 0.f;
    }
  }
  for (int i = t; i < K * 64; i += 256) Ws[i >> 6][i & 63] = W[i];
  __syncthreads();

  const int tr = t >> 4, tc4 = (t & 15) << 2;
  float acc[4][4] = {};
#pragma unroll
  for (int k = 0; k < K; ++k) {
    float4 w = *(const float4*)&Ws[k][tc4];
#pragma unroll
    for (int i = 0; i < 4; ++i) {
      float a = P[tr + 16 * i][k];
      acc[i][0] += a * w.x;
      acc[i][1] += a * w.y;
      acc[i][2] += a * w.z;
      acc[i][3] += a * w.w;
    }
  }

  float s1[4] = {0.f, 0.f, 0.f, 0.f}, s2[4] = {0.f, 0.f, 0.f, 0.f};
  float4 bb = *(const float4*)(b + tc4);
#pragma unroll
  for (int i = 0; i < 4; ++i) {
    int r = r0 + tr + 16 * i;
    if (r < N) {
      float dv = dinv[r];
      float u0 = acc[i][0] * dv + bb.x;
      float u1 = acc[i][1] * dv + bb.y;
      float u2 = acc[i][2] * dv + bb.z;
      float u3 = acc[i][3] * dv + bb.w;
      float4 o;
      o.x = u0 >= 0.f ? u0 : NEG_SLOPE * u0;
      o.y = u1 >= 0.f ? u1 : NEG_SLOPE * u1;
      o.z = u2 >= 0.f ? u2 : NEG_SLOPE * u2;
      o.w = u3 >= 0.f ? u3 : NEG_SLOPE * u3;
      *(float4*)(H + (size_t)r * 64 + tc4) = o;
      s1[0] += o.x; s2[0] += o.x * o.x;
      s1[1] += o.y; s2[1] += o.y * o.y;
      s1[2] += o.z; s2[2] += o.z * o.z;
      s1[3] += o.w; s2[3] += o.w * o.w;
    }
  }
#pragma unroll
  for (int j = 0; j < 4; ++j) {
    red1[tr][tc4 + j] = s1[j];
    red2[tr][tc4 + j] = s2[j];
  }
  __syncthreads();
  if (t < 64) {
    float a1 = 0.f, a2 = 0.f;
#pragma unroll
    for (int i = 0; i < 16; ++i) {
      a1 += red1[i][t];
      a2 += red2[i][t];
    }
    atomicAdd(&bns[t], a1);
    atomicAdd(&bns[64 + t], a2);
  }
}

__global__ __launch_bounds__(64) void bn_finalize(const float* __restrict__ sums,
                                                  const float* __restrict__ g,
                                                  const float* __restrict__ be,
                                                  float* __restrict__ ss, float invN) {
  int c = threadIdx.x;
  float mean = sums[c] * invN;
  float var = sums[64 + c] * invN - mean * mean;
  float sc = g[c] * rsqrtf(var + BN_EPS);
  ss[c] = sc;
  ss[64 + c] = be[c] - mean * sc;
}

// v = (H*scale + shift) * dinv[row]; H <- v (agg self-loop init, in place), HS <- v
__global__ __launch_bounds__(256) void bn_apply(float* __restrict__ H,
                                                const float* __restrict__ ss,
                                                const float* __restrict__ dinv,
                                                float* __restrict__ HS, int N) {
  int i = blockIdx.x * 256 + threadIdx.x;
  if (i >= N * 16) return;
  int r = i >> 4, c4 = (i & 15) << 2;
  float dv = dinv[r];
  float4 h = *(const float4*)(H + (size_t)r * 64 + c4);
  float4 sc = *(const float4*)(ss + c4);
  float4 sh = *(const float4*)(ss + 64 + c4);
  float4 v = make_float4((h.x * sc.x + sh.x) * dv, (h.y * sc.y + sh.y) * dv,
                         (h.z * sc.z + sh.z) * dv, (h.w * sc.w + sh.w) * dv);
  *(float4*)(H + (size_t)r * 64 + c4) = v;
  *(float4*)(HS + (size_t)r * 64 + c4) = v;
}

// OUT[r, c0+c] = dinv[r]*(AGG @ W)[r, c0+c] + b[c0+c]; W is [64][768]
__global__ __launch_bounds__(256) void head_gemm(const float* __restrict__ AGG,
                                                 const float* __restrict__ dinv,
                                                 const float* __restrict__ W,
                                                 const float* __restrict__ b,
                                                 float* __restrict__ OUT, int N) {
  __shared__ __align__(16) float P[64][68];
  __shared__ __align__(16) float Ws[64][64];
  const int t = threadIdx.x;
  const int r0 = blockIdx.x * 64, c0 = blockIdx.y * 64;
  for (int i = t; i < 1024; i += 256) {
    int r = i >> 4, k4 = (i & 15) << 2, gr = r0 + r;
    float4 v = make_float4(0.f, 0.f, 0.f, 0.f);
    if (gr < N) v = *(const float4*)(AGG + (size_t)gr * 64 + k4);
    *(float4*)&P[r][k4] = v;
  }
  for (int i = t; i < 1024; i += 256) {
    int k = i >> 4, c4 = (i & 15) << 2;
    *(float4*)&Ws[k][c4] = *(const float4*)(W + (size_t)k * 768 + c0 + c4);
  }
  __syncthreads();
  const int tr = t >> 4, tc4 = (t & 15) << 2;
  float acc[4][4] = {};
#pragma unroll
  for (int k = 0; k < 64; ++k) {
    float4 w = *(const float4*)&Ws[k][tc4];
#pragma unroll
    for (int i = 0; i < 4; ++i) {
      float a = P[tr + 16 * i][k];
      acc[i][0] += a * w.x;
      acc[i][1] += a * w.y;
      acc[i][2] += a * w.z;
      acc[i][3] += a * w.w;
    }
  }
  float4 bb = *(const float4*)(b + c0 + tc4);
#pragma unroll
  for (int i = 0; i < 4; ++i) {
    int r = r0 + tr + 16 * i;
    if (r < N) {
      float dv = dinv[r];
      float4 o = make_float4(acc[i][0] * dv + bb.x, acc[i][1] * dv + bb.y,
                             acc[i][2] * dv + bb.z, acc[i][3] * dv + bb.w);
      *(float4*)(OUT + (size_t)r * 768 + c0 + tc4) = o;
    }
  }
}

extern "C" void kernel_launch(void* const* d_in, const int* in_sizes, int n_in,
                              void* d_out, int out_size, void* d_ws, size_t ws_size,
                              hipStream_t stream) {
  const float* x   = (const float*)d_in[0];
  const int*   ei  = (const int*)d_in[1];
  const float* W1  = (const float*)d_in[2];
  const float* b1  = (const float*)d_in[3];
  const float* g1  = (const float*)d_in[4];
  const float* be1 = (const float*)d_in[5];
  const float* W2  = (const float*)d_in[6];
  const float* b2  = (const float*)d_in[7];
  const float* g2  = (const float*)d_in[8];
  const float* be2 = (const float*)d_in[9];
  const float* W3  = (const float*)d_in[10];
  const float* b3  = (const float*)d_in[11];
  const float* g3  = (const float*)d_in[12];
  const float* be3 = (const float*)d_in[13];
  const float* Wmu = (const float*)d_in[14];
  const float* bmu = (const float*)d_in[15];
  const float* Wls = (const float*)d_in[16];
  const float* bls = (const float*)d_in[17];

  const int N = in_sizes[0] / 3;
  const int E = in_sizes[1] / 2;
  const int* src = ei;
  const int* dst = ei + E;
  float* out = (float*)d_out;

  float* ws = (float*)d_ws;
  size_t o = 0;
  float* dinv = ws + o; o += (size_t)N;          // deg, then rsqrt in place
  float* hs0  = ws + o; o += (size_t)N * 3;
  float* agg0 = ws + o; o += (size_t)N * 3;
  float* bns  = ws + o; o += 384;
  float* ss   = ws + o; o += 384;
  float* B0   = ws + o; o += (size_t)N * 64;
  float* B1;
  if (ws_size >= (o + (size_t)N * 64) * sizeof(float)) {
    B1 = ws + o;
  } else {
    // Fallback: park B1 in d_out — its last read (final scatter) precedes
    // the head GEMMs that write d_out, and the stream serializes them.
    B1 = out;
  }

  const float invN = 1.0f / (float)N;
  int nbN  = (N + 255) / 256;
  int nbE  = (E + 255) / 256;
  int nb3N = (3 * N + 255) / 256;
  int nbA  = (N * 16 + 255) / 256;
  int gb   = (N + 63) / 64;
  int sb   = (E + 3) / 4;

  init_k<<<nbN, 256, 0, stream>>>(dinv, bns, N);
  degree_count<<<nbE, 256, 0, stream>>>(dst, dinv, E);
  finish_dinv<<<nbN, 256, 0, stream>>>(dinv, N);

  // ---- layer 1 (propagate at 3 channels, then 3->64 GEMM) ----
  scale0<<<nb3N, 256, 0, stream>>>(x, dinv, hs0, agg0, N);
  scatter3<<<nbE, 256, 0, stream>>>(src, dst, hs0, agg0, E);
  gemm_bn<3><<<gb, 256, 0, stream>>>(agg0, dinv, W1, b1, B0, bns + 0, N);
  bn_finalize<<<1, 64, 0, stream>>>(bns + 0, g1, be1, ss + 0, invN);

  // ---- layer 2 ----
  bn_apply<<<nbA, 256, 0, stream>>>(B0, ss + 0, dinv, B1, N);   // B0=agg', B1=hs
  scatter64<<<sb, 256, 0, stream>>>(src, dst, B1, B0, E);
  gemm_bn<64><<<gb, 256, 0, stream>>>(B0, dinv, W2, b2, B1, bns + 128, N);
  bn_finalize<<<1, 64, 0, stream>>>(bns + 128, g2, be2, ss + 128, invN);

  // ---- layer 3 ----
  bn_apply<<<nbA, 256, 0, stream>>>(B1, ss + 128, dinv, B0, N); // B1=agg', B0=hs
  scatter64<<<sb, 256, 0, stream>>>(src, dst, B0, B1, E);
  gemm_bn<64><<<gb, 256, 0, stream>>>(B1, dinv, W3, b3, B0, bns + 256, N);
  bn_finalize<<<1, 64, 0, stream>>>(bns + 256, g3, be3, ss + 256, invN);

  // ---- final propagate (once, 64 ch) + two 64->768 heads ----
  bn_apply<<<nbA, 256, 0, stream>>>(B0, ss + 256, dinv, B1, N); // B0=agg3, B1=hs
  scatter64<<<sb, 256, 0, stream>>>(src, dst, B1, B0, E);       // B0 = final agg

  dim3 hgrid(gb, 12);
  head_gemm<<<hgrid, 256, 0, stream>>>(B0, dinv, Wmu, bmu, out, N);
  head_gemm<<<hgrid, 256, 0, stream>>>(B0, dinv, Wls, bls, out + (size_t)N * 768, N);
}

// Round 4
// 594.238 us; speedup vs baseline: 2.2321x; 2.2321x over previous
//
#include <hip/hip_runtime.h>
#include <cstddef>

// GCN encoder: 3x (GCNConv -> LeakyReLU -> BN) then mu/logstd GCNConv heads.
// prop(x @ W) = prop(x) @ W, so we propagate at the narrowest width (3, 64,
// 64, 64) and fold the symmetric normalization as: hs = h*dinv;
// agg[d] = hs[d] + sum_{e:dst=d} hs[src_e]; final *dinv[d] folded into the
// next GEMM epilogue. Propagation uses a CSR (built per call from edge_index)
// gather instead of atomic scatter.

#define NEG_SLOPE 0.01f
#define BN_EPS 1e-5f

__global__ __launch_bounds__(256) void init_k(int* __restrict__ cnt,
                                              float* __restrict__ bns, int N) {
  int i = blockIdx.x * 256 + threadIdx.x;
  if (i < N) cnt[i] = 0;
  if (i < 384) bns[i] = 0.0f;  // 3 layers x {sum[64], sumsq[64]}
}

__global__ __launch_bounds__(256) void hist_k(const int* __restrict__ dst,
                                              int* __restrict__ cnt, int E) {
  int e = blockIdx.x * 256 + threadIdx.x;
  if (e < E) atomicAdd(&cnt[dst[e]], 1);
}

// Single-block exclusive scan of cnt[N] -> rowptr/cursor, plus dinv = rsqrt(deg+1).
__global__ __launch_bounds__(1024) void scan_k(const int* __restrict__ cnt,
                                               int* __restrict__ rowptr,
                                               int* __restrict__ cursor,
                                               float* __restrict__ dinv,
                                               int N, int E) {
  __shared__ int part[1024];
  const int t = threadIdx.x;
  const int chunk = (N + 1023) / 1024;
  const int beg = t * chunk;
  const int end = (beg + chunk < N) ? beg + chunk : N;
  int s = 0;
  for (int i = beg; i < end; ++i) s += cnt[i];
  part[t] = s;
  __syncthreads();
  for (int off = 1; off < 1024; off <<= 1) {
    int v = (t >= off) ? part[t - off] : 0;
    __syncthreads();
    part[t] += v;
    __syncthreads();
  }
  int run = (t > 0) ? part[t - 1] : 0;
  for (int i = beg; i < end; ++i) {
    rowptr[i] = run;
    cursor[i] = run;
    int c = cnt[i];
    dinv[i] = rsqrtf((float)(c + 1));  // +1 self loop
    run += c;
  }
  if (t == 0) rowptr[N] = E;
}

__global__ __launch_bounds__(256) void fill_k(const int* __restrict__ src,
                                              const int* __restrict__ dst,
                                              int* __restrict__ cursor,
                                              int* __restrict__ eidx, int E) {
  int e = blockIdx.x * 256 + threadIdx.x;
  if (e >= E) return;
  int p = atomicAdd(&cursor[dst[e]], 1);
  eidx[p] = src[e];
}

// hs0 = x * dinv[row]  (3 channels)
__global__ __launch_bounds__(256) void scale0(const float* __restrict__ x,
                                              const float* __restrict__ dinv,
                                              float* __restrict__ hs0, int N) {
  int i = blockIdx.x * 256 + threadIdx.x;
  if (i < N * 3) hs0[i] = x[i] * dinv[i / 3];
}

// agg0[node] = hs0[node] + sum_{in-edges} hs0[src]; one wave per node, 3 ch.
__global__ __launch_bounds__(256) void gather3(const int* __restrict__ rowptr,
                                               const int* __restrict__ eidx,
                                               const float* __restrict__ hs0,
                                               float* __restrict__ agg0, int N) {
  int node = blockIdx.x * 4 + (threadIdx.x >> 6);
  if (node >= N) return;
  int lane = threadIdx.x & 63;
  int beg = rowptr[node], end = rowptr[node + 1];
  float a0 = 0.f, a1 = 0.f, a2 = 0.f;
  for (int e = beg + lane; e < end; e += 64) {
    int s = eidx[e];
    a0 += hs0[s * 3];
    a1 += hs0[s * 3 + 1];
    a2 += hs0[s * 3 + 2];
  }
#pragma unroll
  for (int off = 32; off; off >>= 1) {
    a0 += __shfl_down(a0, off);
    a1 += __shfl_down(a1, off);
    a2 += __shfl_down(a2, off);
  }
  if (lane == 0) {
    agg0[node * 3]     = a0 + hs0[node * 3];
    agg0[node * 3 + 1] = a1 + hs0[node * 3 + 1];
    agg0[node * 3 + 2] = a2 + hs0[node * 3 + 2];
  }
}

// agg[node][c] = hs[node][c] + sum hs[src][c]; one wave per node, lane = ch.
__global__ __launch_bounds__(256) void gather64(const int* __restrict__ rowptr,
                                                const int* __restrict__ eidx,
                                                const float* __restrict__ hs,
                                                float* __restrict__ agg, int N) {
  int node = blockIdx.x * 4 + (threadIdx.x >> 6);
  if (node >= N) return;
  int lane = threadIdx.x & 63;
  int beg = rowptr[node], end = rowptr[node + 1];
  float acc = hs[(size_t)node * 64 + lane];  // self loop
  int e = beg;
  for (; e + 3 < end; e += 4) {
    int s0 = eidx[e], s1 = eidx[e + 1], s2 = eidx[e + 2], s3 = eidx[e + 3];
    float v0 = hs[(size_t)s0 * 64 + lane];
    float v1 = hs[(size_t)s1 * 64 + lane];
    float v2 = hs[(size_t)s2 * 64 + lane];
    float v3 = hs[(size_t)s3 * 64 + lane];
    acc += v0 + v1 + v2 + v3;
  }
  for (; e < end; ++e) acc += hs[(size_t)eidx[e] * 64 + lane];
  agg[(size_t)node * 64 + lane] = acc;
}

// H = LeakyReLU(dinv[r]*(AGG @ W) + b) + per-channel BN sum/sumsq partials.
// 64x64 tile, 256 threads, 4x4 per thread. BN reduction reuses Ws LDS.
template <int K>
__global__ __launch_bounds__(256, 4) void gemm_bn(
    const float* __restrict__ AGG, const float* __restrict__ dinv,
    const float* __restrict__ W /*[K][64]*/, const float* __restrict__ b,
    float* __restrict__ H, float* __restrict__ bns, int N) {
  __shared__ __align__(16) float P[64][68];
  __shared__ __align__(16) float Ws[64][64];
  const int t = threadIdx.x;
  const int r0 = blockIdx.x * 64;

  if (K == 64) {
    for (int i = t; i < 1024; i += 256) {
      int r = i >> 4, k4 = (i & 15) << 2, gr = r0 + r;
      float4 v = make_float4(0.f, 0.f, 0.f, 0.f);
      if (gr < N) v = *(const float4*)(AGG + (size_t)gr * 64 + k4);
      *(float4*)&P[r][k4] = v;
    }
  } else {
    for (int i = t; i < 64 * 64; i += 256) {
      int r = i >> 6, k = i & 63, gr = r0 + r;
      P[r][k] = (k < K && gr < N) ? AGG[(size_t)gr * K + k] : 0.f;
    }
  }
  for (int i = t; i < K * 64; i += 256) Ws[i >> 6][i & 63] = W[i];
  __syncthreads();

  const int tr = t >> 4, tc4 = (t & 15) << 2;
  float acc[4][4] = {};
#pragma unroll 8
  for (int k = 0; k < K; ++k) {
    float4 w = *(const float4*)&Ws[k][tc4];
#pragma unroll
    for (int i = 0; i < 4; ++i) {
      float a = P[tr + 16 * i][k];
      acc[i][0] += a * w.x;
      acc[i][1] += a * w.y;
      acc[i][2] += a * w.z;
      acc[i][3] += a * w.w;
    }
  }

  float s1[4] = {0.f, 0.f, 0.f, 0.f}, s2[4] = {0.f, 0.f, 0.f, 0.f};
  float4 bb = *(const float4*)(b + tc4);
#pragma unroll
  for (int i = 0; i < 4; ++i) {
    int r = r0 + tr + 16 * i;
    if (r < N) {
      float dv = dinv[r];
      float u0 = acc[i][0] * dv + bb.x;
      float u1 = acc[i][1] * dv + bb.y;
      float u2 = acc[i][2] * dv + bb.z;
      float u3 = acc[i][3] * dv + bb.w;
      float4 o;
      o.x = u0 >= 0.f ? u0 : NEG_SLOPE * u0;
      o.y = u1 >= 0.f ? u1 : NEG_SLOPE * u1;
      o.z = u2 >= 0.f ? u2 : NEG_SLOPE * u2;
      o.w = u3 >= 0.f ? u3 : NEG_SLOPE * u3;
      *(float4*)(H + (size_t)r * 64 + tc4) = o;
      s1[0] += o.x; s2[0] += o.x * o.x;
      s1[1] += o.y; s2[1] += o.y * o.y;
      s1[2] += o.z; s2[2] += o.z * o.z;
      s1[3] += o.w; s2[3] += o.w * o.w;
    }
  }
  __syncthreads();  // done reading Ws; reuse it for the BN reduction
  float (*red1)[64] = (float(*)[64]) & Ws[0][0];
  float (*red2)[64] = (float(*)[64]) & Ws[16][0];
#pragma unroll
  for (int j = 0; j < 4; ++j) {
    red1[tr][tc4 + j] = s1[j];
    red2[tr][tc4 + j] = s2[j];
  }
  __syncthreads();
  if (t < 64) {
    float a1 = 0.f, a2 = 0.f;
#pragma unroll
    for (int i = 0; i < 16; ++i) {
      a1 += red1[i][t];
      a2 += red2[i][t];
    }
    atomicAdd(&bns[t], a1);
    atomicAdd(&bns[64 + t], a2);
  }
}

__global__ __launch_bounds__(64) void bn_finalize(const float* __restrict__ sums,
                                                  const float* __restrict__ g,
                                                  const float* __restrict__ be,
                                                  float* __restrict__ ss, float invN) {
  int c = threadIdx.x;
  float mean = sums[c] * invN;
  float var = sums[64 + c] * invN - mean * mean;
  float sc = g[c] * rsqrtf(var + BN_EPS);
  ss[c] = sc;
  ss[64 + c] = be[c] - mean * sc;
}

// HS = (H*scale + shift) * dinv[row]
__global__ __launch_bounds__(256) void bn_apply(const float* __restrict__ H,
                                                const float* __restrict__ ss,
                                                const float* __restrict__ dinv,
                                                float* __restrict__ HS, int N) {
  int i = blockIdx.x * 256 + threadIdx.x;
  if (i >= N * 16) return;
  int r = i >> 4, c4 = (i & 15) << 2;
  float dv = dinv[r];
  float4 h = *(const float4*)(H + (size_t)r * 64 + c4);
  float4 sc = *(const float4*)(ss + c4);
  float4 sh = *(const float4*)(ss + 64 + c4);
  float4 v = make_float4((h.x * sc.x + sh.x) * dv, (h.y * sc.y + sh.y) * dv,
                         (h.z * sc.z + sh.z) * dv, (h.w * sc.w + sh.w) * dv);
  *(float4*)(HS + (size_t)r * 64 + c4) = v;
}

// Both heads in one kernel. 64 rows x 128 cols per block; y: 0-5 mu, 6-11 ls.
// Per thread: 4 rows x 8 cols. W staged in two 32-k chunks (LDS 33.8 KB).
__global__ __launch_bounds__(256, 4) void head_gemm2(
    const float* __restrict__ AGG, const float* __restrict__ dinv,
    const float* __restrict__ Wmu, const float* __restrict__ bmu,
    const float* __restrict__ Wls, const float* __restrict__ bls,
    float* __restrict__ OUT, int N) {
  __shared__ __align__(16) float P[64][68];
  __shared__ __align__(16) float Ws[32][128];
  const int t = threadIdx.x;
  const int r0 = blockIdx.x * 64;
  const int yy = blockIdx.y;
  const int head = (yy >= 6) ? 1 : 0;
  const int c0 = (head ? yy - 6 : yy) * 128;
  const float* W = head ? Wls : Wmu;
  const float* b = head ? bls : bmu;
  float* O = OUT + (head ? (size_t)N * 768 : 0);

  for (int i = t; i < 1024; i += 256) {
    int r = i >> 4, k4 = (i & 15) << 2, gr = r0 + r;
    float4 v = make_float4(0.f, 0.f, 0.f, 0.f);
    if (gr < N) v = *(const float4*)(AGG + (size_t)gr * 64 + k4);
    *(float4*)&P[r][k4] = v;
  }

  const int tr = t >> 4;       // rows tr, tr+16, tr+32, tr+48
  const int tc = t & 15;       // cols tc*4..+3 and 64+tc*4..+3
  float acc[4][8] = {};

  for (int kk = 0; kk < 64; kk += 32) {
    __syncthreads();
    for (int i = t; i < 1024; i += 256) {  // 32 k x 128 c as float4s
      int k = i >> 5, c4 = (i & 31) << 2;
      *(float4*)&Ws[k][c4] = *(const float4*)(W + (size_t)(kk + k) * 768 + c0 + c4);
    }
    __syncthreads();
#pragma unroll 4
    for (int k = 0; k < 32; ++k) {
      float4 w0 = *(const float4*)&Ws[k][tc * 4];
      float4 w1 = *(const float4*)&Ws[k][64 + tc * 4];
      float a[4];
      a[0] = P[tr][kk + k];
      a[1] = P[tr + 16][kk + k];
      a[2] = P[tr + 32][kk + k];
      a[3] = P[tr + 48][kk + k];
#pragma unroll
      for (int i = 0; i < 4; ++i) {
        acc[i][0] += a[i] * w0.x;
        acc[i][1] += a[i] * w0.y;
        acc[i][2] += a[i] * w0.z;
        acc[i][3] += a[i] * w0.w;
        acc[i][4] += a[i] * w1.x;
        acc[i][5] += a[i] * w1.y;
        acc[i][6] += a[i] * w1.z;
        acc[i][7] += a[i] * w1.w;
      }
    }
  }

  float4 bb0 = *(const float4*)(b + c0 + tc * 4);
  float4 bb1 = *(const float4*)(b + c0 + 64 + tc * 4);
#pragma unroll
  for (int i = 0; i < 4; ++i) {
    int r = r0 + tr + 16 * i;
    if (r < N) {
      float dv = dinv[r];
      float4 o0 = make_float4(acc[i][0] * dv + bb0.x, acc[i][1] * dv + bb0.y,
                              acc[i][2] * dv + bb0.z, acc[i][3] * dv + bb0.w);
      float4 o1 = make_float4(acc[i][4] * dv + bb1.x, acc[i][5] * dv + bb1.y,
                              acc[i][6] * dv + bb1.z, acc[i][7] * dv + bb1.w);
      *(float4*)(O + (size_t)r * 768 + c0 + tc * 4) = o0;
      *(float4*)(O + (size_t)r * 768 + c0 + 64 + tc * 4) = o1;
    }
  }
}

extern "C" void kernel_launch(void* const* d_in, const int* in_sizes, int n_in,
                              void* d_out, int out_size, void* d_ws, size_t ws_size,
                              hipStream_t stream) {
  const float* x   = (const float*)d_in[0];
  const int*   ei  = (const int*)d_in[1];
  const float* W1  = (const float*)d_in[2];
  const float* b1  = (const float*)d_in[3];
  const float* g1  = (const float*)d_in[4];
  const float* be1 = (const float*)d_in[5];
  const float* W2  = (const float*)d_in[6];
  const float* b2  = (const float*)d_in[7];
  const float* g2  = (const float*)d_in[8];
  const float* be2 = (const float*)d_in[9];
  const float* W3  = (const float*)d_in[10];
  const float* b3  = (const float*)d_in[11];
  const float* g3  = (const float*)d_in[12];
  const float* be3 = (const float*)d_in[13];
  const float* Wmu = (const float*)d_in[14];
  const float* bmu = (const float*)d_in[15];
  const float* Wls = (const float*)d_in[16];
  const float* bls = (const float*)d_in[17];

  const int N = in_sizes[0] / 3;
  const int E = in_sizes[1] / 2;
  const int* src = ei;
  const int* dst = ei + E;
  float* out = (float*)d_out;

  char* ws = (char*)d_ws;
  size_t o = 0;
  float* dinv = (float*)(ws + o); o += (size_t)N * 4;
  float* bns  = (float*)(ws + o); o += 384 * 4;
  float* ss   = (float*)(ws + o); o += 384 * 4;
  float* hs0  = (float*)(ws + o); o += (size_t)N * 3 * 4;
  float* agg0 = (float*)(ws + o); o += (size_t)N * 3 * 4;
  int* cnt    = (int*)(ws + o);   o += (size_t)N * 4;
  int* rowptr = (int*)(ws + o);   o += ((size_t)N + 1) * 4;
  int* cursor = (int*)(ws + o);   o += (size_t)N * 4;
  int* eidx   = (int*)(ws + o);   o += (size_t)E * 4;
  float* B0   = (float*)(ws + o); o += (size_t)N * 64 * 4;
  float* B1;
  if (ws_size >= o + (size_t)N * 64 * 4) {
    B1 = (float*)(ws + o);
  } else {
    // Fallback: park B1 in d_out — its last read (final gather64) precedes
    // the head GEMM that writes d_out, and the stream serializes them.
    B1 = out;
  }

  const float invN = 1.0f / (float)N;
  int nbN  = (N + 255) / 256;
  int nbE  = (E + 255) / 256;
  int nb3N = (3 * N + 255) / 256;
  int nbA  = (N * 16 + 255) / 256;
  int gb   = (N + 63) / 64;
  int wb   = (N + 3) / 4;

  // CSR build (edge_index is constant across all 4 propagations)
  init_k<<<nbN, 256, 0, stream>>>(cnt, bns, N);
  hist_k<<<nbE, 256, 0, stream>>>(dst, cnt, E);
  scan_k<<<1, 1024, 0, stream>>>(cnt, rowptr, cursor, dinv, N, E);
  fill_k<<<nbE, 256, 0, stream>>>(src, dst, cursor, eidx, E);

  // ---- layer 1 (propagate at 3 channels, then 3->64 GEMM) ----
  scale0<<<nb3N, 256, 0, stream>>>(x, dinv, hs0, N);
  gather3<<<wb, 256, 0, stream>>>(rowptr, eidx, hs0, agg0, N);
  gemm_bn<3><<<gb, 256, 0, stream>>>(agg0, dinv, W1, b1, B0, bns + 0, N);
  bn_finalize<<<1, 64, 0, stream>>>(bns + 0, g1, be1, ss + 0, invN);

  // ---- layer 2 ----
  bn_apply<<<nbA, 256, 0, stream>>>(B0, ss + 0, dinv, B1, N);
  gather64<<<wb, 256, 0, stream>>>(rowptr, eidx, B1, B0, N);
  gemm_bn<64><<<gb, 256, 0, stream>>>(B0, dinv, W2, b2, B1, bns + 128, N);
  bn_finalize<<<1, 64, 0, stream>>>(bns + 128, g2, be2, ss + 128, invN);

  // ---- layer 3 ----
  bn_apply<<<nbA, 256, 0, stream>>>(B1, ss + 128, dinv, B0, N);
  gather64<<<wb, 256, 0, stream>>>(rowptr, eidx, B0, B1, N);
  gemm_bn<64><<<gb, 256, 0, stream>>>(B1, dinv, W3, b3, B0, bns + 256, N);
  bn_finalize<<<1, 64, 0, stream>>>(bns + 256, g3, be3, ss + 256, invN);

  // ---- final propagate (once, 64 ch) + fused mu/logstd heads ----
  bn_apply<<<nbA, 256, 0, stream>>>(B0, ss + 256, dinv, B1, N);
  gather64<<<wb, 256, 0, stream>>>(rowptr, eidx, B1, B0, N);

  dim3 hgrid(gb, 12);
  head_gemm2<<<hgrid, 256, 0, stream>>>(B0, dinv, Wmu, bmu, Wls, bls, out, N);
}

// Round 5
// 578.256 us; speedup vs baseline: 2.2938x; 1.0276x over previous
//
#include <hip/hip_runtime.h>
#include <cstddef>

// GCN encoder, BN-folded formulation.
// prop(h)[d] = dinv[d]*(P(h)[d] @ W) + b, P(h)[d] = sum_{s in N(d)+self} dinv[s]*h[s].
// BN(z) = z*sc + sh  (affine, per channel)  =>
// P(BN(o))[d] = sc (.) P(o)[d] + q[d]*sh,  q[d] = sum dinv[s]  (graph-only).
// So each layer's GEMM consumes G = gather(Z) with Z = o*dinv, uses
// W' = diag(sc)@W and c' = sh@W, epilogue u = dv*acc + dv*q[r]*c'[c] + b[c].
// BN stats (of o = LeakyReLU pre-scale) accumulate in the GEMM epilogue.

#define NEG_SLOPE 0.01f
#define BN_EPS 1e-5f

__global__ __launch_bounds__(256) void init_k(int* __restrict__ cnt,
                                              float* __restrict__ bns, int N) {
  int i = blockIdx.x * 256 + threadIdx.x;
  if (i < N) cnt[i] = 0;
  if (i < 384) bns[i] = 0.0f;  // 3 layers x {sum[64], sumsq[64]}
}

__global__ __launch_bounds__(256) void hist_k(const int* __restrict__ dst,
                                              int* __restrict__ cnt, int E) {
  int e = blockIdx.x * 256 + threadIdx.x;
  if (e < E) atomicAdd(&cnt[dst[e]], 1);
}

// Single-block exclusive scan of cnt[N] -> rowptr/cursor, plus dinv = rsqrt(deg+1).
__global__ __launch_bounds__(1024) void scan_k(const int* __restrict__ cnt,
                                               int* __restrict__ rowptr,
                                               int* __restrict__ cursor,
                                               float* __restrict__ dinv,
                                               int N, int E) {
  __shared__ int part[1024];
  const int t = threadIdx.x;
  const int chunk = (N + 1023) / 1024;
  const int beg = t * chunk;
  const int end = (beg + chunk < N) ? beg + chunk : N;
  int s = 0;
  for (int i = beg; i < end; ++i) s += cnt[i];
  part[t] = s;
  __syncthreads();
  for (int off = 1; off < 1024; off <<= 1) {
    int v = (t >= off) ? part[t - off] : 0;
    __syncthreads();
    part[t] += v;
    __syncthreads();
  }
  int run = (t > 0) ? part[t - 1] : 0;
  for (int i = beg; i < end; ++i) {
    rowptr[i] = run;
    cursor[i] = run;
    int c = cnt[i];
    dinv[i] = rsqrtf((float)(c + 1));  // +1 self loop
    run += c;
  }
  if (t == 0) rowptr[N] = E;
}

__global__ __launch_bounds__(256) void fill_k(const int* __restrict__ src,
                                              const int* __restrict__ dst,
                                              int* __restrict__ cursor,
                                              int* __restrict__ eidx, int E) {
  int e = blockIdx.x * 256 + threadIdx.x;
  if (e >= E) return;
  int p = atomicAdd(&cursor[dst[e]], 1);
  eidx[p] = src[e];
}

// Layer 1 fully fused: per node (one wave, grid-stride):
//   agg(3ch) = x[node]*dv + sum_e x[src]*dinv[src];  q[node] = dv + sum dinv[src]
//   u = dv*(agg @ W1) + b1; o = LeakyReLU(u); Z1 = o*dv; BN stats of o.
__global__ __launch_bounds__(256) void l1_fused(
    const int* __restrict__ rowptr, const int* __restrict__ eidx,
    const float* __restrict__ x, const float* __restrict__ dinv,
    const float* __restrict__ W1, const float* __restrict__ b1,
    float* __restrict__ Z, float* __restrict__ q, float* __restrict__ bns, int N) {
  const int t = threadIdx.x, lane = t & 63, wid = t >> 6;
  const int gw = blockIdx.x * 4 + wid;
  const int nw = gridDim.x * 4;
  const float w0 = W1[lane], w1 = W1[64 + lane], w2 = W1[128 + lane];
  const float bb = b1[lane];
  float s1 = 0.f, s2 = 0.f;
  for (int node = gw; node < N; node += nw) {
    int beg = rowptr[node], end = rowptr[node + 1];
    float a0 = 0.f, a1 = 0.f, a2 = 0.f, aq = 0.f;
    for (int e = beg + lane; e < end; e += 64) {
      int s = eidx[e];
      float dv = dinv[s];
      a0 += x[s * 3] * dv;
      a1 += x[s * 3 + 1] * dv;
      a2 += x[s * 3 + 2] * dv;
      aq += dv;
    }
#pragma unroll
    for (int off = 32; off; off >>= 1) {
      a0 += __shfl_xor(a0, off);
      a1 += __shfl_xor(a1, off);
      a2 += __shfl_xor(a2, off);
      aq += __shfl_xor(aq, off);
    }
    float dv = dinv[node];
    a0 += x[node * 3] * dv;
    a1 += x[node * 3 + 1] * dv;
    a2 += x[node * 3 + 2] * dv;
    aq += dv;
    float u = dv * (a0 * w0 + a1 * w1 + a2 * w2) + bb;
    float o = u >= 0.f ? u : NEG_SLOPE * u;
    Z[(size_t)node * 64 + lane] = o * dv;
    s1 += o;
    s2 += o * o;
    if (lane == 0) q[node] = aq;
  }
  __shared__ float red[8][64];
  red[wid][lane] = s1;
  red[4 + wid][lane] = s2;
  __syncthreads();
  if (t < 64) {
    atomicAdd(&bns[t], red[0][t] + red[1][t] + red[2][t] + red[3][t]);
    atomicAdd(&bns[64 + t], red[4][t] + red[5][t] + red[6][t] + red[7][t]);
  }
}

// G[node][c] = Z[node][c] + sum Z[src][c]; one wave per node, lane = channel.
__global__ __launch_bounds__(256) void gather64(const int* __restrict__ rowptr,
                                                const int* __restrict__ eidx,
                                                const float* __restrict__ Z,
                                                float* __restrict__ G, int N) {
  int node = blockIdx.x * 4 + (threadIdx.x >> 6);
  if (node >= N) return;
  int lane = threadIdx.x & 63;
  int beg = rowptr[node], end = rowptr[node + 1];
  float acc = Z[(size_t)node * 64 + lane];  // self loop
  int e = beg;
  for (; e + 3 < end; e += 4) {
    int s0 = eidx[e], s1 = eidx[e + 1], s2 = eidx[e + 2], s3 = eidx[e + 3];
    float v0 = Z[(size_t)s0 * 64 + lane];
    float v1 = Z[(size_t)s1 * 64 + lane];
    float v2 = Z[(size_t)s2 * 64 + lane];
    float v3 = Z[(size_t)s3 * 64 + lane];
    acc += v0 + v1 + v2 + v3;
  }
  for (; e < end; ++e) acc += Z[(size_t)eidx[e] * 64 + lane];
  G[(size_t)node * 64 + lane] = acc;
}

// sc/sh from bns, then W'[k][c] = sc[k]*W[k][c] (64x64), c'[c] = sum_k sh[k]*W[k][c].
__global__ __launch_bounds__(256) void prep_small(
    const float* __restrict__ bns, const float* __restrict__ g,
    const float* __restrict__ be, const float* __restrict__ W,
    float* __restrict__ Wc, float* __restrict__ cx, float invN) {
  __shared__ float sc[64], sh[64], part[4][64];
  int t = threadIdx.x;
  if (t < 64) {
    float mean = bns[t] * invN;
    float var = bns[64 + t] * invN - mean * mean;
    float s = g[t] * rsqrtf(var + BN_EPS);
    sc[t] = s;
    sh[t] = be[t] - mean * s;
  }
  __syncthreads();
  int c = t & 63, kq = t >> 6;
  float p = 0.f;
  for (int k = kq * 16; k < kq * 16 + 16; ++k) {
    float w = W[k * 64 + c];
    Wc[k * 64 + c] = sc[k] * w;
    p += sh[k] * w;
  }
  part[kq][c] = p;
  __syncthreads();
  if (t < 64) cx[t] = part[0][t] + part[1][t] + part[2][t] + part[3][t];
}

// Same for the two 64x768 head weights. grid.x = 12: blocks 0-5 mu, 6-11 ls (128 cols each).
__global__ __launch_bounds__(256) void prep_head(
    const float* __restrict__ bns, const float* __restrict__ g,
    const float* __restrict__ be, const float* __restrict__ Wmu,
    const float* __restrict__ Wls, float* __restrict__ Wmc,
    float* __restrict__ Wlc, float* __restrict__ cmu, float* __restrict__ cls,
    float invN) {
  __shared__ float sc[64], sh[64], part[2][128];
  int t = threadIdx.x;
  if (t < 64) {
    float mean = bns[t] * invN;
    float var = bns[64 + t] * invN - mean * mean;
    float s = g[t] * rsqrtf(var + BN_EPS);
    sc[t] = s;
    sh[t] = be[t] - mean * s;
  }
  __syncthreads();
  int blk = blockIdx.x;
  int head = blk >= 6 ? 1 : 0;
  int c0 = (head ? blk - 6 : blk) * 128;
  const float* W = head ? Wls : Wmu;
  float* Wc = head ? Wlc : Wmc;
  float* cx = head ? cls : cmu;
  int c = c0 + (t & 127), kh = t >> 7;
  float p = 0.f;
  for (int k = kh * 32; k < kh * 32 + 32; ++k) {
    float w = W[(size_t)k * 768 + c];
    Wc[(size_t)k * 768 + c] = sc[k] * w;
    p += sh[k] * w;
  }
  part[kh][t & 127] = p;
  __syncthreads();
  if (t < 128) cx[c0 + t] = part[0][t] + part[1][t];
}

// Z_next = LeakyReLU(dv*(G @ Wc) + dv*q[r]*cx + b) * dv, plus BN stats of o.
__global__ __launch_bounds__(256, 4) void gemm_bnq(
    const float* __restrict__ G, const float* __restrict__ dinv,
    const float* __restrict__ q, const float* __restrict__ Wc,
    const float* __restrict__ cx, const float* __restrict__ b,
    float* __restrict__ Z, float* __restrict__ bns, int N) {
  __shared__ __align__(16) float P[64][68];
  __shared__ __align__(16) float Ws[64][64];
  const int t = threadIdx.x;
  const int r0 = blockIdx.x * 64;

  for (int i = t; i < 1024; i += 256) {
    int r = i >> 4, k4 = (i & 15) << 2, gr = r0 + r;
    float4 v = make_float4(0.f, 0.f, 0.f, 0.f);
    if (gr < N) v = *(const float4*)(G + (size_t)gr * 64 + k4);
    *(float4*)&P[r][k4] = v;
  }
  for (int i = t; i < 4096; i += 256) Ws[i >> 6][i & 63] = Wc[i];
  __syncthreads();

  const int tr = t >> 4, tc4 = (t & 15) << 2;
  float acc[4][4] = {};
#pragma unroll 8
  for (int k = 0; k < 64; ++k) {
    float4 w = *(const float4*)&Ws[k][tc4];
#pragma unroll
    for (int i = 0; i < 4; ++i) {
      float a = P[tr + 16 * i][k];
      acc[i][0] += a * w.x;
      acc[i][1] += a * w.y;
      acc[i][2] += a * w.z;
      acc[i][3] += a * w.w;
    }
  }

  float s1[4] = {0.f, 0.f, 0.f, 0.f}, s2[4] = {0.f, 0.f, 0.f, 0.f};
  float4 bb = *(const float4*)(b + tc4);
  float4 cc = *(const float4*)(cx + tc4);
#pragma unroll
  for (int i = 0; i < 4; ++i) {
    int r = r0 + tr + 16 * i;
    if (r < N) {
      float dv = dinv[r];
      float dq = dv * q[r];
      float u0 = acc[i][0] * dv + dq * cc.x + bb.x;
      float u1 = acc[i][1] * dv + dq * cc.y + bb.y;
      float u2 = acc[i][2] * dv + dq * cc.z + bb.z;
      float u3 = acc[i][3] * dv + dq * cc.w + bb.w;
      float o0 = u0 >= 0.f ? u0 : NEG_SLOPE * u0;
      float o1 = u1 >= 0.f ? u1 : NEG_SLOPE * u1;
      float o2 = u2 >= 0.f ? u2 : NEG_SLOPE * u2;
      float o3 = u3 >= 0.f ? u3 : NEG_SLOPE * u3;
      float4 z = make_float4(o0 * dv, o1 * dv, o2 * dv, o3 * dv);
      *(float4*)(Z + (size_t)r * 64 + tc4) = z;
      s1[0] += o0; s2[0] += o0 * o0;
      s1[1] += o1; s2[1] += o1 * o1;
      s1[2] += o2; s2[2] += o2 * o2;
      s1[3] += o3; s2[3] += o3 * o3;
    }
  }
  __syncthreads();  // Ws no longer needed; reuse for BN reduction
  float (*red1)[64] = (float(*)[64]) & Ws[0][0];
  float (*red2)[64] = (float(*)[64]) & Ws[16][0];
#pragma unroll
  for (int j = 0; j < 4; ++j) {
    red1[tr][tc4 + j] = s1[j];
    red2[tr][tc4 + j] = s2[j];
  }
  __syncthreads();
  if (t < 64) {
    float a1 = 0.f, a2 = 0.f;
#pragma unroll
    for (int i = 0; i < 16; ++i) {
      a1 += red1[i][t];
      a2 += red2[i][t];
    }
    atomicAdd(&bns[t], a1);
    atomicAdd(&bns[64 + t], a2);
  }
}

// Both heads. 64 rows x 128 cols per block; y: 0-5 mu, 6-11 ls.
// out = dv*(G @ Wc) + dv*q[r]*cx + b.
__global__ __launch_bounds__(256, 4) void head_gemm2(
    const float* __restrict__ G, const float* __restrict__ dinv,
    const float* __restrict__ q, const float* __restrict__ Wmc,
    const float* __restrict__ cmu, const float* __restrict__ bmu,
    const float* __restrict__ Wlc, const float* __restrict__ cls,
    const float* __restrict__ bls, float* __restrict__ OUT, int N) {
  __shared__ __align__(16) float P[64][68];
  __shared__ __align__(16) float Ws[32][128];
  const int t = threadIdx.x;
  const int r0 = blockIdx.x * 64;
  const int yy = blockIdx.y;
  const int head = (yy >= 6) ? 1 : 0;
  const int c0 = (head ? yy - 6 : yy) * 128;
  const float* W = head ? Wlc : Wmc;
  const float* cx = head ? cls : cmu;
  const float* b = head ? bls : bmu;
  float* O = OUT + (head ? (size_t)N * 768 : 0);

  for (int i = t; i < 1024; i += 256) {
    int r = i >> 4, k4 = (i & 15) << 2, gr = r0 + r;
    float4 v = make_float4(0.f, 0.f, 0.f, 0.f);
    if (gr < N) v = *(const float4*)(G + (size_t)gr * 64 + k4);
    *(float4*)&P[r][k4] = v;
  }

  const int tr = t >> 4;
  const int tc = t & 15;
  float acc[4][8] = {};

  for (int kk = 0; kk < 64; kk += 32) {
    __syncthreads();
    for (int i = t; i < 1024; i += 256) {
      int k = i >> 5, c4 = (i & 31) << 2;
      *(float4*)&Ws[k][c4] = *(const float4*)(W + (size_t)(kk + k) * 768 + c0 + c4);
    }
    __syncthreads();
#pragma unroll 4
    for (int k = 0; k < 32; ++k) {
      float4 w0 = *(const float4*)&Ws[k][tc * 4];
      float4 w1 = *(const float4*)&Ws[k][64 + tc * 4];
      float a[4];
      a[0] = P[tr][kk + k];
      a[1] = P[tr + 16][kk + k];
      a[2] = P[tr + 32][kk + k];
      a[3] = P[tr + 48][kk + k];
#pragma unroll
      for (int i = 0; i < 4; ++i) {
        acc[i][0] += a[i] * w0.x;
        acc[i][1] += a[i] * w0.y;
        acc[i][2] += a[i] * w0.z;
        acc[i][3] += a[i] * w0.w;
        acc[i][4] += a[i] * w1.x;
        acc[i][5] += a[i] * w1.y;
        acc[i][6] += a[i] * w1.z;
        acc[i][7] += a[i] * w1.w;
      }
    }
  }

  float4 bb0 = *(const float4*)(b + c0 + tc * 4);
  float4 bb1 = *(const float4*)(b + c0 + 64 + tc * 4);
  float4 cc0 = *(const float4*)(cx + c0 + tc * 4);
  float4 cc1 = *(const float4*)(cx + c0 + 64 + tc * 4);
#pragma unroll
  for (int i = 0; i < 4; ++i) {
    int r = r0 + tr + 16 * i;
    if (r < N) {
      float dv = dinv[r];
      float dq = dv * q[r];
      float4 o0 = make_float4(acc[i][0] * dv + dq * cc0.x + bb0.x,
                              acc[i][1] * dv + dq * cc0.y + bb0.y,
                              acc[i][2] * dv + dq * cc0.z + bb0.z,
                              acc[i][3] * dv + dq * cc0.w + bb0.w);
      float4 o1 = make_float4(acc[i][4] * dv + dq * cc1.x + bb1.x,
                              acc[i][5] * dv + dq * cc1.y + bb1.y,
                              acc[i][6] * dv + dq * cc1.z + bb1.z,
                              acc[i][7] * dv + dq * cc1.w + bb1.w);
      *(float4*)(O + (size_t)r * 768 + c0 + tc * 4) = o0;
      *(float4*)(O + (size_t)r * 768 + c0 + 64 + tc * 4) = o1;
    }
  }
}

extern "C" void kernel_launch(void* const* d_in, const int* in_sizes, int n_in,
                              void* d_out, int out_size, void* d_ws, size_t ws_size,
                              hipStream_t stream) {
  const float* x   = (const float*)d_in[0];
  const int*   ei  = (const int*)d_in[1];
  const float* W1  = (const float*)d_in[2];
  const float* b1  = (const float*)d_in[3];
  const float* g1  = (const float*)d_in[4];
  const float* be1 = (const float*)d_in[5];
  const float* W2  = (const float*)d_in[6];
  const float* b2  = (const float*)d_in[7];
  const float* g2  = (const float*)d_in[8];
  const float* be2 = (const float*)d_in[9];
  const float* W3  = (const float*)d_in[10];
  const float* b3  = (const float*)d_in[11];
  const float* g3  = (const float*)d_in[12];
  const float* be3 = (const float*)d_in[13];
  const float* Wmu = (const float*)d_in[14];
  const float* bmu = (const float*)d_in[15];
  const float* Wls = (const float*)d_in[16];
  const float* bls = (const float*)d_in[17];

  const int N = in_sizes[0] / 3;
  const int E = in_sizes[1] / 2;
  const int* src = ei;
  const int* dst = ei + E;
  float* out = (float*)d_out;

  char* ws = (char*)d_ws;
  size_t o = 0;
  float* dinv = (float*)(ws + o); o += (size_t)N * 4;
  float* qv   = (float*)(ws + o); o += (size_t)N * 4;
  float* bns  = (float*)(ws + o); o += 384 * 4;
  float* W2c  = (float*)(ws + o); o += 4096 * 4;
  float* c2   = (float*)(ws + o); o += 64 * 4;
  float* W3c  = (float*)(ws + o); o += 4096 * 4;
  float* c3   = (float*)(ws + o); o += 64 * 4;
  float* Wmc  = (float*)(ws + o); o += (size_t)64 * 768 * 4;
  float* cmu  = (float*)(ws + o); o += 768 * 4;
  float* Wlc  = (float*)(ws + o); o += (size_t)64 * 768 * 4;
  float* cls  = (float*)(ws + o); o += 768 * 4;
  int* cnt    = (int*)(ws + o);   o += (size_t)N * 4;
  int* rowptr = (int*)(ws + o);   o += ((size_t)N + 1) * 4;
  int* cursor = (int*)(ws + o);   o += (size_t)N * 4;
  int* eidx   = (int*)(ws + o);   o += (size_t)E * 4;
  float* B0   = (float*)(ws + o); o += (size_t)N * 64 * 4;
  float* B1   = (float*)(ws + o); o += (size_t)N * 64 * 4;
  // ws_size observed ~1.2 GB; total used ~31 MB.

  const float invN = 1.0f / (float)N;
  int nbN = (N + 255) / 256;
  int nbE = (E + 255) / 256;
  int gb  = (N + 63) / 64;
  int wb  = (N + 3) / 4;

  // CSR build (edge_index constant across all 4 propagations)
  init_k<<<nbN, 256, 0, stream>>>(cnt, bns, N);
  hist_k<<<nbE, 256, 0, stream>>>(dst, cnt, E);
  scan_k<<<1, 1024, 0, stream>>>(cnt, rowptr, cursor, dinv, N, E);
  fill_k<<<nbE, 256, 0, stream>>>(src, dst, cursor, eidx, E);

  // ---- layer 1: fused gather(3ch)+GEMM+stats, writes Z1=B0 and q ----
  l1_fused<<<1024, 256, 0, stream>>>(rowptr, eidx, x, dinv, W1, b1, B0, qv, bns, N);
  prep_small<<<1, 256, 0, stream>>>(bns + 0, g1, be1, W2, W2c, c2, invN);

  // ---- layer 2 ----
  gather64<<<wb, 256, 0, stream>>>(rowptr, eidx, B0, B1, N);      // B1 = G1
  gemm_bnq<<<gb, 256, 0, stream>>>(B1, dinv, qv, W2c, c2, b2, B0, bns + 128, N);
  prep_small<<<1, 256, 0, stream>>>(bns + 128, g2, be2, W3, W3c, c3, invN);

  // ---- layer 3 ----
  gather64<<<wb, 256, 0, stream>>>(rowptr, eidx, B0, B1, N);      // B1 = G2
  gemm_bnq<<<gb, 256, 0, stream>>>(B1, dinv, qv, W3c, c3, b3, B0, bns + 256, N);
  prep_head<<<12, 256, 0, stream>>>(bns + 256, g3, be3, Wmu, Wls, Wmc, Wlc, cmu, cls, invN);

  // ---- final propagate + fused mu/logstd heads ----
  gather64<<<wb, 256, 0, stream>>>(rowptr, eidx, B0, B1, N);      // B1 = G3
  dim3 hgrid(gb, 12);
  head_gemm2<<<hgrid, 256, 0, stream>>>(B1, dinv, qv, Wmc, cmu, bmu, Wlc, cls, bls, out, N);
}

// Round 8
// 444.689 us; speedup vs baseline: 2.9828x; 1.3004x over previous
//
#include <hip/hip_runtime.h>
#include <cstddef>

// GCN encoder, BN-folded formulation.
// prop(h)[d] = dinv[d]*(P(h)[d] @ W) + b, P(h)[d] = sum_{s in N(d)+self} dinv[s]*h[s].
// BN(z) = z*sc + sh  =>  P(BN(o))[d] = sc (.) P(o)[d] + q[d]*sh, q graph-only.
// Each layer's GEMM consumes G = gather(Z), Z = o*dinv, with W' = diag(sc)@W,
// c' = sh@W, epilogue u = dv*acc + dv*q[r]*c'[c] + b[c]. BN stats in epilogue.

#define NEG_SLOPE 0.01f
#define BN_EPS 1e-5f

__global__ __launch_bounds__(256) void init_k(int* __restrict__ cnt,
                                              float* __restrict__ bns, int N) {
  int i = blockIdx.x * 256 + threadIdx.x;
  if (i < N) cnt[i] = 0;
  if (i < 384) bns[i] = 0.0f;  // 3 layers x {sum[64], sumsq[64]}
}

__global__ __launch_bounds__(256) void hist_k(const int* __restrict__ dst,
                                              int* __restrict__ cnt, int E) {
  int e = blockIdx.x * 256 + threadIdx.x;
  if (e < E) atomicAdd(&cnt[dst[e]], 1);
}

// Multi-block scan, phase A: block-local exclusive scan of cnt into pre
// (=rowptr used as scratch), block totals into bsum.
__global__ __launch_bounds__(1024) void scanA(const int* __restrict__ cnt,
                                              int* __restrict__ pre,
                                              int* __restrict__ bsum, int N) {
  __shared__ int sh[1024];
  const int t = threadIdx.x;
  const int i = blockIdx.x * 1024 + t;
  int c = (i < N) ? cnt[i] : 0;
  sh[t] = c;
  __syncthreads();
  for (int off = 1; off < 1024; off <<= 1) {
    int v = (t >= off) ? sh[t - off] : 0;
    __syncthreads();
    sh[t] += v;
    __syncthreads();
  }
  if (i < N) pre[i] = sh[t] - c;  // exclusive
  if (t == 1023) bsum[blockIdx.x] = sh[t];
}

// Phase B: single-wave exclusive scan of nb (<=64) block sums in place.
__global__ __launch_bounds__(64) void scanB(int* __restrict__ bsum, int nb) {
  int t = threadIdx.x;
  int orig = (t < nb) ? bsum[t] : 0;
  int v = orig;
#pragma unroll
  for (int off = 1; off < 64; off <<= 1) {
    int u = __shfl_up(v, off);
    if (t >= off) v += u;
  }
  if (t < nb) bsum[t] = v - orig;
}

// Phase C: rowptr = pre + bsum[blk]; cursor copy; dinv = rsqrt(deg+1).
__global__ __launch_bounds__(256) void scanC(const int* __restrict__ cnt,
                                             int* __restrict__ rowptr,
                                             int* __restrict__ cursor,
                                             const int* __restrict__ bsum,
                                             float* __restrict__ dinv,
                                             int N, int E) {
  int i = blockIdx.x * 256 + threadIdx.x;
  if (i < N) {
    int rp = rowptr[i] + bsum[i >> 10];
    rowptr[i] = rp;
    cursor[i] = rp;
    dinv[i] = rsqrtf((float)(cnt[i] + 1));  // +1 self loop
  }
  if (i == 0) rowptr[N] = E;
}

__global__ __launch_bounds__(256) void fill_k(const int* __restrict__ src,
                                              const int* __restrict__ dst,
                                              int* __restrict__ cursor,
                                              int* __restrict__ eidx, int E) {
  int e = blockIdx.x * 256 + threadIdx.x;
  if (e >= E) return;
  int p = atomicAdd(&cursor[dst[e]], 1);
  eidx[p] = src[e];
}

// Layer 1 fully fused: per node (one wave, grid-stride):
//   agg(3ch) = x[node]*dv + sum_e x[src]*dinv[src];  q[node] = dv + sum dinv[src]
//   u = dv*(agg @ W1) + b1; o = LeakyReLU(u); Z1 = o*dv; BN stats of o.
__global__ __launch_bounds__(256) void l1_fused(
    const int* __restrict__ rowptr, const int* __restrict__ eidx,
    const float* __restrict__ x, const float* __restrict__ dinv,
    const float* __restrict__ W1, const float* __restrict__ b1,
    float* __restrict__ Z, float* __restrict__ q, float* __restrict__ bns, int N) {
  const int t = threadIdx.x, lane = t & 63, wid = t >> 6;
  const int gw = blockIdx.x * 4 + wid;
  const int nw = gridDim.x * 4;
  const float w0 = W1[lane], w1 = W1[64 + lane], w2 = W1[128 + lane];
  const float bb = b1[lane];
  float s1 = 0.f, s2 = 0.f;
  for (int node = gw; node < N; node += nw) {
    int beg = rowptr[node], end = rowptr[node + 1];
    float a0 = 0.f, a1 = 0.f, a2 = 0.f, aq = 0.f;
    for (int e = beg + lane; e < end; e += 64) {
      int s = eidx[e];
      float dv = dinv[s];
      a0 += x[s * 3] * dv;
      a1 += x[s * 3 + 1] * dv;
      a2 += x[s * 3 + 2] * dv;
      aq += dv;
    }
#pragma unroll
    for (int off = 32; off; off >>= 1) {
      a0 += __shfl_xor(a0, off);
      a1 += __shfl_xor(a1, off);
      a2 += __shfl_xor(a2, off);
      aq += __shfl_xor(aq, off);
    }
    float dv = dinv[node];
    a0 += x[node * 3] * dv;
    a1 += x[node * 3 + 1] * dv;
    a2 += x[node * 3 + 2] * dv;
    aq += dv;
    float u = dv * (a0 * w0 + a1 * w1 + a2 * w2) + bb;
    float o = u >= 0.f ? u : NEG_SLOPE * u;
    Z[(size_t)node * 64 + lane] = o * dv;
    s1 += o;
    s2 += o * o;
    if (lane == 0) q[node] = aq;
  }
  __shared__ float red[8][64];
  red[wid][lane] = s1;
  red[4 + wid][lane] = s2;
  __syncthreads();
  if (t < 64) {
    atomicAdd(&bns[t], red[0][t] + red[1][t] + red[2][t] + red[3][t]);
    atomicAdd(&bns[64 + t], red[4][t] + red[5][t] + red[6][t] + red[7][t]);
  }
}

// G[node][c] = Z[node][c] + sum Z[src][c]; one wave per node.
// lane = (slot: lane>>4) x (4 channels: (lane&15)*4). 4 edges/iter, unroll 2
// -> 8 edges in flight per wave (16B/lane float4 loads; eidx read is a
// 16-lane broadcast). Cross-slot reduce via shfl_xor(16|32).
__global__ __launch_bounds__(256) void gather64(const int* __restrict__ rowptr,
                                                const int* __restrict__ eidx,
                                                const float* __restrict__ Z,
                                                float* __restrict__ G, int N) {
  int node = blockIdx.x * 4 + (threadIdx.x >> 6);
  if (node >= N) return;
  int lane = threadIdx.x & 63;
  int slot = lane >> 4;
  int c4 = (lane & 15) << 2;
  int beg = rowptr[node], end = rowptr[node + 1];
  float ax = 0.f, ay = 0.f, az = 0.f, aw = 0.f;
  int e = beg + slot;
  for (; e + 4 < end; e += 8) {
    int s0 = eidx[e], s1 = eidx[e + 4];
    float4 v0 = *(const float4*)(Z + (size_t)s0 * 64 + c4);
    float4 v1 = *(const float4*)(Z + (size_t)s1 * 64 + c4);
    ax += v0.x + v1.x;
    ay += v0.y + v1.y;
    az += v0.z + v1.z;
    aw += v0.w + v1.w;
  }
  if (e < end) {
    int s0 = eidx[e];
    float4 v0 = *(const float4*)(Z + (size_t)s0 * 64 + c4);
    ax += v0.x; ay += v0.y; az += v0.z; aw += v0.w;
  }
#pragma unroll
  for (int off = 16; off < 64; off <<= 1) {
    ax += __shfl_xor(ax, off);
    ay += __shfl_xor(ay, off);
    az += __shfl_xor(az, off);
    aw += __shfl_xor(aw, off);
  }
  if (slot == 0) {
    float4 self = *(const float4*)(Z + (size_t)node * 64 + c4);
    float4 o = make_float4(ax + self.x, ay + self.y, az + self.z, aw + self.w);
    *(float4*)(G + (size_t)node * 64 + c4) = o;
  }
}

// sc/sh from bns, then W'[k][c] = sc[k]*W[k][c] (64x64), c'[c] = sum_k sh[k]*W[k][c].
__global__ __launch_bounds__(256) void prep_small(
    const float* __restrict__ bns, const float* __restrict__ g,
    const float* __restrict__ be, const float* __restrict__ W,
    float* __restrict__ Wc, float* __restrict__ cx, float invN) {
  __shared__ float sc[64], sh[64], part[4][64];
  int t = threadIdx.x;
  if (t < 64) {
    float mean = bns[t] * invN;
    float var = bns[64 + t] * invN - mean * mean;
    float s = g[t] * rsqrtf(var + BN_EPS);
    sc[t] = s;
    sh[t] = be[t] - mean * s;
  }
  __syncthreads();
  int c = t & 63, kq = t >> 6;
  float p = 0.f;
  for (int k = kq * 16; k < kq * 16 + 16; ++k) {
    float w = W[k * 64 + c];
    Wc[k * 64 + c] = sc[k] * w;
    p += sh[k] * w;
  }
  part[kq][c] = p;
  __syncthreads();
  if (t < 64) cx[t] = part[0][t] + part[1][t] + part[2][t] + part[3][t];
}

// Same for the two 64x768 head weights. grid.x = 12: 0-5 mu, 6-11 ls (128 cols each).
__global__ __launch_bounds__(256) void prep_head(
    const float* __restrict__ bns, const float* __restrict__ g,
    const float* __restrict__ be, const float* __restrict__ Wmu,
    const float* __restrict__ Wls, float* __restrict__ Wmc,
    float* __restrict__ Wlc, float* __restrict__ cmu, float* __restrict__ cls,
    float invN) {
  __shared__ float sc[64], sh[64], part[2][128];
  int t = threadIdx.x;
  if (t < 64) {
    float mean = bns[t] * invN;
    float var = bns[64 + t] * invN - mean * mean;
    float s = g[t] * rsqrtf(var + BN_EPS);
    sc[t] = s;
    sh[t] = be[t] - mean * s;
  }
  __syncthreads();
  int blk = blockIdx.x;
  int head = blk >= 6 ? 1 : 0;
  int c0 = (head ? blk - 6 : blk) * 128;
  const float* W = head ? Wls : Wmu;
  float* Wc = head ? Wlc : Wmc;
  float* cx = head ? cls : cmu;
  int c = c0 + (t & 127), kh = t >> 7;
  float p = 0.f;
  for (int k = kh * 32; k < kh * 32 + 32; ++k) {
    float w = W[(size_t)k * 768 + c];
    Wc[(size_t)k * 768 + c] = sc[k] * w;
    p += sh[k] * w;
  }
  part[kh][t & 127] = p;
  __syncthreads();
  if (t < 128) cx[c0 + t] = part[0][t] + part[1][t];
}

// Z_next = LeakyReLU(dv*(G @ Wc) + dv*q[r]*cx + b) * dv, plus BN stats of o.
__global__ __launch_bounds__(256, 4) void gemm_bnq(
    const float* __restrict__ G, const float* __restrict__ dinv,
    const float* __restrict__ q, const float* __restrict__ Wc,
    const float* __restrict__ cx, const float* __restrict__ b,
    float* __restrict__ Z, float* __restrict__ bns, int N) {
  __shared__ __align__(16) float P[64][68];
  __shared__ __align__(16) float Ws[64][64];
  const int t = threadIdx.x;
  const int r0 = blockIdx.x * 64;

  for (int i = t; i < 1024; i += 256) {
    int r = i >> 4, k4 = (i & 15) << 2, gr = r0 + r;
    float4 v = make_float4(0.f, 0.f, 0.f, 0.f);
    if (gr < N) v = *(const float4*)(G + (size_t)gr * 64 + k4);
    *(float4*)&P[r][k4] = v;
  }
  for (int i = t; i < 4096; i += 256) Ws[i >> 6][i & 63] = Wc[i];
  __syncthreads();

  const int tr = t >> 4, tc4 = (t & 15) << 2;
  float acc[4][4] = {};
#pragma unroll 8
  for (int k = 0; k < 64; ++k) {
    float4 w = *(const float4*)&Ws[k][tc4];
#pragma unroll
    for (int i = 0; i < 4; ++i) {
      float a = P[tr + 16 * i][k];
      acc[i][0] += a * w.x;
      acc[i][1] += a * w.y;
      acc[i][2] += a * w.z;
      acc[i][3] += a * w.w;
    }
  }

  float s1[4] = {0.f, 0.f, 0.f, 0.f}, s2[4] = {0.f, 0.f, 0.f, 0.f};
  float4 bb = *(const float4*)(b + tc4);
  float4 cc = *(const float4*)(cx + tc4);
#pragma unroll
  for (int i = 0; i < 4; ++i) {
    int r = r0 + tr + 16 * i;
    if (r < N) {
      float dv = dinv[r];
      float dq = dv * q[r];
      float u0 = acc[i][0] * dv + dq * cc.x + bb.x;
      float u1 = acc[i][1] * dv + dq * cc.y + bb.y;
      float u2 = acc[i][2] * dv + dq * cc.z + bb.z;
      float u3 = acc[i][3] * dv + dq * cc.w + bb.w;
      float o0 = u0 >= 0.f ? u0 : NEG_SLOPE * u0;
      float o1 = u1 >= 0.f ? u1 : NEG_SLOPE * u1;
      float o2 = u2 >= 0.f ? u2 : NEG_SLOPE * u2;
      float o3 = u3 >= 0.f ? u3 : NEG_SLOPE * u3;
      float4 z = make_float4(o0 * dv, o1 * dv, o2 * dv, o3 * dv);
      *(float4*)(Z + (size_t)r * 64 + tc4) = z;
      s1[0] += o0; s2[0] += o0 * o0;
      s1[1] += o1; s2[1] += o1 * o1;
      s1[2] += o2; s2[2] += o2 * o2;
      s1[3] += o3; s2[3] += o3 * o3;
    }
  }
  __syncthreads();  // Ws no longer needed; reuse for BN reduction
  float (*red1)[64] = (float(*)[64]) & Ws[0][0];
  float (*red2)[64] = (float(*)[64]) & Ws[16][0];
#pragma unroll
  for (int j = 0; j < 4; ++j) {
    red1[tr][tc4 + j] = s1[j];
    red2[tr][tc4 + j] = s2[j];
  }
  __syncthreads();
  if (t < 64) {
    float a1 = 0.f, a2 = 0.f;
#pragma unroll
    for (int i = 0; i < 16; ++i) {
      a1 += red1[i][t];
      a2 += red2[i][t];
    }
    atomicAdd(&bns[t], a1);
    atomicAdd(&bns[64 + t], a2);
  }
}

// Both heads. 64 rows x 128 cols per block; y: 0-5 mu, 6-11 ls.
// out = dv*(G @ Wc) + dv*q[r]*cx + b.
__global__ __launch_bounds__(256, 4) void head_gemm2(
    const float* __restrict__ G, const float* __restrict__ dinv,
    const float* __restrict__ q, const float* __restrict__ Wmc,
    const float* __restrict__ cmu, const float* __restrict__ bmu,
    const float* __restrict__ Wlc, const float* __restrict__ cls,
    const float* __restrict__ bls, float* __restrict__ OUT, int N) {
  __shared__ __align__(16) float P[64][68];
  __shared__ __align__(16) float Ws[32][128];
  const int t = threadIdx.x;
  const int r0 = blockIdx.x * 64;
  const int yy = blockIdx.y;
  const int head = (yy >= 6) ? 1 : 0;
  const int c0 = (head ? yy - 6 : yy) * 128;
  const float* W = head ? Wlc : Wmc;
  const float* cx = head ? cls : cmu;
  const float* b = head ? bls : bmu;
  float* O = OUT + (head ? (size_t)N * 768 : 0);

  for (int i = t; i < 1024; i += 256) {
    int r = i >> 4, k4 = (i & 15) << 2, gr = r0 + r;
    float4 v = make_float4(0.f, 0.f, 0.f, 0.f);
    if (gr < N) v = *(const float4*)(G + (size_t)gr * 64 + k4);
    *(float4*)&P[r][k4] = v;
  }

  const int tr = t >> 4;
  const int tc = t & 15;
  float acc[4][8] = {};

  for (int kk = 0; kk < 64; kk += 32) {
    __syncthreads();
    for (int i = t; i < 1024; i += 256) {
      int k = i >> 5, c4 = (i & 31) << 2;
      *(float4*)&Ws[k][c4] = *(const float4*)(W + (size_t)(kk + k) * 768 + c0 + c4);
    }
    __syncthreads();
#pragma unroll 4
    for (int k = 0; k < 32; ++k) {
      float4 w0 = *(const float4*)&Ws[k][tc * 4];
      float4 w1 = *(const float4*)&Ws[k][64 + tc * 4];
      float a[4];
      a[0] = P[tr][kk + k];
      a[1] = P[tr + 16][kk + k];
      a[2] = P[tr + 32][kk + k];
      a[3] = P[tr + 48][kk + k];
#pragma unroll
      for (int i = 0; i < 4; ++i) {
        acc[i][0] += a[i] * w0.x;
        acc[i][1] += a[i] * w0.y;
        acc[i][2] += a[i] * w0.z;
        acc[i][3] += a[i] * w0.w;
        acc[i][4] += a[i] * w1.x;
        acc[i][5] += a[i] * w1.y;
        acc[i][6] += a[i] * w1.z;
        acc[i][7] += a[i] * w1.w;
      }
    }
  }

  float4 bb0 = *(const float4*)(b + c0 + tc * 4);
  float4 bb1 = *(const float4*)(b + c0 + 64 + tc * 4);
  float4 cc0 = *(const float4*)(cx + c0 + tc * 4);
  float4 cc1 = *(const float4*)(cx + c0 + 64 + tc * 4);
#pragma unroll
  for (int i = 0; i < 4; ++i) {
    int r = r0 + tr + 16 * i;
    if (r < N) {
      float dv = dinv[r];
      float dq = dv * q[r];
      float4 o0 = make_float4(acc[i][0] * dv + dq * cc0.x + bb0.x,
                              acc[i][1] * dv + dq * cc0.y + bb0.y,
                              acc[i][2] * dv + dq * cc0.z + bb0.z,
                              acc[i][3] * dv + dq * cc0.w + bb0.w);
      float4 o1 = make_float4(acc[i][4] * dv + dq * cc1.x + bb1.x,
                              acc[i][5] * dv + dq * cc1.y + bb1.y,
                              acc[i][6] * dv + dq * cc1.z + bb1.z,
                              acc[i][7] * dv + dq * cc1.w + bb1.w);
      *(float4*)(O + (size_t)r * 768 + c0 + tc * 4) = o0;
      *(float4*)(O + (size_t)r * 768 + c0 + 64 + tc * 4) = o1;
    }
  }
}

extern "C" void kernel_launch(void* const* d_in, const int* in_sizes, int n_in,
                              void* d_out, int out_size, void* d_ws, size_t ws_size,
                              hipStream_t stream) {
  const float* x   = (const float*)d_in[0];
  const int*   ei  = (const int*)d_in[1];
  const float* W1  = (const float*)d_in[2];
  const float* b1  = (const float*)d_in[3];
  const float* g1  = (const float*)d_in[4];
  const float* be1 = (const float*)d_in[5];
  const float* W2  = (const float*)d_in[6];
  const float* b2  = (const float*)d_in[7];
  const float* g2  = (const float*)d_in[8];
  const float* be2 = (const float*)d_in[9];
  const float* W3  = (const float*)d_in[10];
  const float* b3  = (const float*)d_in[11];
  const float* g3  = (const float*)d_in[12];
  const float* be3 = (const float*)d_in[13];
  const float* Wmu = (const float*)d_in[14];
  const float* bmu = (const float*)d_in[15];
  const float* Wls = (const float*)d_in[16];
  const float* bls = (const float*)d_in[17];

  const int N = in_sizes[0] / 3;
  const int E = in_sizes[1] / 2;
  const int* src = ei;
  const int* dst = ei + E;
  float* out = (float*)d_out;

  char* ws = (char*)d_ws;
  size_t o = 0;
  float* dinv = (float*)(ws + o); o += (size_t)N * 4;
  float* qv   = (float*)(ws + o); o += (size_t)N * 4;
  float* bns  = (float*)(ws + o); o += 384 * 4;
  float* W2c  = (float*)(ws + o); o += 4096 * 4;
  float* c2   = (float*)(ws + o); o += 64 * 4;
  float* W3c  = (float*)(ws + o); o += 4096 * 4;
  float* c3   = (float*)(ws + o); o += 64 * 4;
  float* Wmc  = (float*)(ws + o); o += (size_t)64 * 768 * 4;
  float* cmu  = (float*)(ws + o); o += 768 * 4;
  float* Wlc  = (float*)(ws + o); o += (size_t)64 * 768 * 4;
  float* cls  = (float*)(ws + o); o += 768 * 4;
  int* cnt    = (int*)(ws + o);   o += (size_t)N * 4;
  int* rowptr = (int*)(ws + o);   o += ((size_t)N + 1) * 4;
  int* cursor = (int*)(ws + o);   o += (size_t)N * 4;
  int* bsum   = (int*)(ws + o);   o += 64 * 4;
  int* eidx   = (int*)(ws + o);   o += (size_t)E * 4;
  float* B0   = (float*)(ws + o); o += (size_t)N * 64 * 4;
  float* B1   = (float*)(ws + o); o += (size_t)N * 64 * 4;
  // ws_size observed ~1.2 GB; total used ~31 MB.

  const float invN = 1.0f / (float)N;
  int nbN = (N + 255) / 256;
  int nbE = (E + 255) / 256;
  int gb  = (N + 63) / 64;
  int wb  = (N + 3) / 4;
  int sbA = (N + 1023) / 1024;

  // CSR build (edge_index constant across all 4 propagations)
  init_k<<<nbN, 256, 0, stream>>>(cnt, bns, N);
  hist_k<<<nbE, 256, 0, stream>>>(dst, cnt, E);
  scanA<<<sbA, 1024, 0, stream>>>(cnt, rowptr, bsum, N);
  scanB<<<1, 64, 0, stream>>>(bsum, sbA);
  scanC<<<nbN, 256, 0, stream>>>(cnt, rowptr, cursor, bsum, dinv, N, E);
  fill_k<<<nbE, 256, 0, stream>>>(src, dst, cursor, eidx, E);

  // ---- layer 1: fused gather(3ch)+GEMM+stats, writes Z1=B0 and q ----
  l1_fused<<<1024, 256, 0, stream>>>(rowptr, eidx, x, dinv, W1, b1, B0, qv, bns, N);
  prep_small<<<1, 256, 0, stream>>>(bns + 0, g1, be1, W2, W2c, c2, invN);

  // ---- layer 2 ----
  gather64<<<wb, 256, 0, stream>>>(rowptr, eidx, B0, B1, N);      // B1 = G1
  gemm_bnq<<<gb, 256, 0, stream>>>(B1, dinv, qv, W2c, c2, b2, B0, bns + 128, N);
  prep_small<<<1, 256, 0, stream>>>(bns + 128, g2, be2, W3, W3c, c3, invN);

  // ---- layer 3 ----
  gather64<<<wb, 256, 0, stream>>>(rowptr, eidx, B0, B1, N);      // B1 = G2
  gemm_bnq<<<gb, 256, 0, stream>>>(B1, dinv, qv, W3c, c3, b3, B0, bns + 256, N);
  prep_head<<<12, 256, 0, stream>>>(bns + 256, g3, be3, Wmu, Wls, Wmc, Wlc, cmu, cls, invN);

  // ---- final propagate + fused mu/logstd heads ----
  gather64<<<wb, 256, 0, stream>>>(rowptr, eidx, B0, B1, N);      // B1 = G3
  dim3 hgrid(gb, 12);
  head_gemm2<<<hgrid, 256, 0, stream>>>(B1, dinv, qv, Wmc, cmu, bmu, Wlc, cls, bls, out, N);
}